// Round 2
// baseline (214.476 us; speedup 1.0000x reference)
//
#include <hip/hip_runtime.h>
#include <math.h>

// YOLO loss: pred/target (BATCH,7,7,30) f32, choice (BATCH,7,7) i32
// -> 4 scalars (loc, cls, obj, noobj).
// Round-11: replace reg-staged prefetch + __syncthreads (which forces
// s_waitcnt vmcnt(0) every iteration -> full drain of the prefetched
// chunk, the m97-style structural stall) with:
//   - global_load_lds (16B) direct staging, double-buffered LDS
//   - raw s_barrier + counted s_waitcnt vmcnt(N), never 0 mid-loop
//   - choice routed through LDS too (no reg-carried vmem deps)
// Per-wave issue counts per chunk are exactly {8,8,8,7}: 30 data slots
// (1 KB each: pred 15 + target 15) + half-slot for choice (wave2).
// Depth-2: chunk c+2G issued while c+1G stays in flight across barriers.
// Accumulation order bitwise-identical to round-7 baseline (same CPB,
// GRID, lane->cell map, compute code, reduction tree).

typedef float vf4 __attribute__((ext_vector_type(4)));

constexpr int NCH = 30;    // 5*B + C
constexpr int CC  = 20;    // classes
constexpr int ROW = 8;     // floats per block's partial row (32 B)
constexpr int T   = 256;   // threads per block (4 waves)
constexpr int CPB = 128;   // cells per chunk
constexpr int GRID = 1280; // 1280 blocks (2 resident/CU now, LDS-bound)

constexpr int DATA_B   = CPB * NCH * 4;         // 15360 B per array per chunk
constexpr int CHOICE_B = CPB * 4;               // 512 B
constexpr int BUF_B    = 2 * DATA_B + CHOICE_B; // 31232 B per buffer
constexpr int NSLOT    = (2 * DATA_B) / 1024;   // 30 full 1-KB data slots

__device__ __forceinline__ void gl_lds16(const void* g, void* l) {
    __builtin_amdgcn_global_load_lds(
        (__attribute__((address_space(1))) void*)g,
        (__attribute__((address_space(3))) void*)l, 16, 0, 0);
}

// Issue one chunk-group: per-wave vmem ops = {8,8,8,7} (w2 carries choice).
__device__ __forceinline__ void issue_group(
    const char* __restrict__ predB, const char* __restrict__ targetB,
    const char* __restrict__ choiceB, long long cc, long long ncells,
    int tid, char* ldsbuf)
{
    const int w = tid >> 6, l = tid & 63;
    const long long cbyteA  = cc * (long long)DATA_B;
    const long long cbyteC  = cc * (long long)CHOICE_B;
    const long long nbytesA = ncells * (long long)(NCH * 4);
    const long long nbytesC = ncells * 4ll;
    #pragma unroll
    for (int jj = 0; jj < 8; ++jj) {
        int s = w + jj * 4;                    // wave-uniform slot id
        if (s < NSLOT) {                       // data slot: 1 KB, 64 lanes x 16 B
            int f = s * 1024 + l * 16;         // byte in combined pred||target
            const char* src;
            long long off;
            if (f < DATA_B) { off = cbyteA + f;            src = predB; }
            else            { off = cbyteA + (f - DATA_B); src = targetB; }
            if (off + 16 > nbytesA) off = nbytesA - 16;    // tail clamp (unused here)
            gl_lds16(src + off, ldsbuf + f);
        } else if (s == NSLOT) {               // choice half-slot (wave 2 only)
            if (l < 32) {                      // 32 lanes x 16 B = 512 B
                long long off = cbyteC + (long long)l * 16;
                if (off + 16 > nbytesC) off = nbytesC - 16;
                gl_lds16(choiceB + off, ldsbuf + 2 * DATA_B + l * 16);
            }
        }
        // s == 31 (wave 3, jj==7): no-op -> wave3 issues 7
    }
}

__device__ __forceinline__ void wait_newer(int w, bool has_next) {
    if (!has_next) { asm volatile("s_waitcnt vmcnt(0)" ::: "memory"); return; }
    if (w == 3) asm volatile("s_waitcnt vmcnt(7)" ::: "memory");
    else        asm volatile("s_waitcnt vmcnt(8)" ::: "memory");
}

__global__ __launch_bounds__(T) void yolo_main(
    const float* __restrict__ pred, const float* __restrict__ target,
    const int* __restrict__ choice, float* __restrict__ ws,
    int ncells, int nchunks)
{
    __shared__ __align__(16) char sbuf[2 * BUF_B];   // 62464 B double buffer
    __shared__ float red[4][6];
    const int tid = threadIdx.x;
    const int w   = tid >> 6;

    const char* predB   = (const char*)pred;
    const char* targetB = (const char*)target;
    const char* choiceB = (const char*)choice;

    float a_loc = 0.f, a_ce = 0.f, a_obj = 0.f, a_no = 0.f;
    float a_nob = 0.f, a_nno = 0.f;

    long long c = blockIdx.x;
    int p = 0;
    if (c < nchunks) {
        issue_group(predB, targetB, choiceB, c, ncells, tid, sbuf);
        if (c + GRID < nchunks)
            issue_group(predB, targetB, choiceB, c + GRID, ncells, tid, sbuf + BUF_B);
    }

    for (; c < nchunks; c += GRID) {
        bool has_next = (c + GRID < nchunks);
        wait_newer(w, has_next);               // counted: older group resident
        __builtin_amdgcn_s_barrier();          // all waves' slots for c done
        asm volatile("" ::: "memory");

        if (tid < CPB && c * CPB + tid < (long long)ncells) {
            const float* bp  = (const float*)(sbuf + p * BUF_B);
            const float* sp  = bp + tid * NCH;
            const float* stt = bp + (DATA_B / 4) + tid * NCH;
            int myc = ((const int*)(sbuf + p * BUF_B + 2 * DATA_B))[tid];
            float pv[NCH], t[NCH];
            #pragma unroll
            for (int i = 0; i < NCH / 2; ++i) {
                float2 v = *(const float2*)&sp[2 * i];  pv[2*i] = v.x; pv[2*i+1] = v.y;
            }
            #pragma unroll
            for (int i = 0; i < NCH / 2; ++i) {
                float2 u = *(const float2*)&stt[2 * i]; t[2*i] = u.x; t[2*i+1] = u.y;
            }
            bool csel = myc != 0;

            float tconf = t[4];
            bool  obj = tconf > 0.0f;
            float m = obj ? 1.0f : 0.0f;

            float pxy0 = csel ? pv[0] : pv[5];
            float pxy1 = csel ? pv[1] : pv[6];
            float pwh0 = csel ? pv[2] : pv[7];
            float pwh1 = csel ? pv[3] : pv[8];
            float pobj = csel ? pv[4] : pv[9];
            float txy0 = csel ? t[0] : t[5];
            float txy1 = csel ? t[1] : t[6];
            float twh0 = csel ? t[2] : t[7];
            float twh1 = csel ? t[3] : t[8];
            if (!obj) { twh0 = 1.0f; twh1 = 1.0f; }
            float tobj = csel ? tconf : t[9];

            float dx = pxy0 - txy0, dy = pxy1 - txy1;
            float dw = pwh0 - sqrtf(twh0), dh = pwh1 - sqrtf(twh1);
            a_loc += m * (0.5f * (dx*dx + dy*dy) + 0.5f * (dw*dw + dh*dh));

            float dob = pobj - tobj;
            a_obj += m * dob * dob;

            float nm = (tconf == 0.0f) ? 1.0f : 0.0f;
            float d4 = pv[4] - tconf, d9 = pv[9] - t[9];
            a_no += nm * (d4 * d4 + d9 * d9);

            a_nob += m;
            a_nno += nm;

            int   tcls  = 0;
            float tbest = t[10];
            #pragma unroll
            for (int i = 1; i < CC; ++i) {
                float v = t[10 + i];
                if (v > tbest) { tbest = v; tcls = i; }
            }
            float mx = pv[10];
            #pragma unroll
            for (int i = 1; i < CC; ++i) mx = fmaxf(mx, pv[10 + i]);
            float e[CC];
            float Z = 0.f;
            #pragma unroll
            for (int i = 0; i < CC; ++i) { e[i] = __expf(pv[10+i] - mx); Z += e[i]; }
            float rZ = 1.0f / Z;
            float Z2 = 0.f, sm_t = 0.f;
            #pragma unroll
            for (int i = 0; i < CC; ++i) {
                float sm = e[i] * rZ;          // in (0,1] -> exp safe
                Z2 += __expf(sm);
                if (i == tcls) sm_t = sm;
            }
            a_ce += m * (__logf(Z2) - sm_t);
        }

        asm volatile("" ::: "memory");
        __builtin_amdgcn_s_barrier();          // all waves done reading buf[p]
        asm volatile("" ::: "memory");

        if (c + 2 * (long long)GRID < nchunks) // refill buf[p] with chunk c+2G
            issue_group(predB, targetB, choiceB, c + 2 * GRID, ncells, tid,
                        sbuf + p * BUF_B);
        p ^= 1;
    }

    // wave(64) shuffle reduction of the 6 accumulators
    #pragma unroll
    for (int off = 32; off > 0; off >>= 1) {
        a_loc += __shfl_down(a_loc, off);
        a_ce  += __shfl_down(a_ce,  off);
        a_obj += __shfl_down(a_obj, off);
        a_no  += __shfl_down(a_no,  off);
        a_nob += __shfl_down(a_nob, off);
        a_nno += __shfl_down(a_nno, off);
    }

    int lane = tid & 63;
    if (lane == 0) {
        red[w][0] = a_loc; red[w][1] = a_ce;  red[w][2] = a_obj;
        red[w][3] = a_no;  red[w][4] = a_nob; red[w][5] = a_nno;
    }
    __syncthreads();
    if (tid < 6) {   // NO atomics: private row per block
        float v = red[0][tid] + red[1][tid] + red[2][tid] + red[3][tid];
        ws[(size_t)blockIdx.x * ROW + tid] = v;
    }
}

__global__ __launch_bounds__(256) void yolo_reduce(
    const float* __restrict__ ws, float* __restrict__ out, int nb)
{
    float s[6] = {0.f, 0.f, 0.f, 0.f, 0.f, 0.f};
    for (int b = threadIdx.x; b < nb; b += 256) {
        #pragma unroll
        for (int j = 0; j < 6; ++j) s[j] += ws[(size_t)b * ROW + j];
    }
    #pragma unroll
    for (int off = 32; off > 0; off >>= 1) {
        #pragma unroll
        for (int j = 0; j < 6; ++j) s[j] += __shfl_down(s[j], off);
    }
    __shared__ float red[4][6];
    int wave = threadIdx.x >> 6;
    int lane = threadIdx.x & 63;
    if (lane == 0) {
        #pragma unroll
        for (int j = 0; j < 6; ++j) red[wave][j] = s[j];
    }
    __syncthreads();
    if (threadIdx.x == 0) {
        float t[6];
        #pragma unroll
        for (int j = 0; j < 6; ++j)
            t[j] = red[0][j] + red[1][j] + red[2][j] + red[3][j];
        out[0] = 5.0f * t[0];                     // loc_loss  (L_COORD = 5)
        out[1] = t[1] / fmaxf(t[4], 1.0f);        // cls_loss
        out[2] = t[2];                            // obj_loss
        out[3] = 0.5f * t[3] / fmaxf(t[5], 1.0f); // noobj_loss (L_NOOBJ = 0.5)
    }
}

extern "C" void kernel_launch(void* const* d_in, const int* in_sizes, int n_in,
                              void* d_out, int out_size, void* d_ws, size_t ws_size,
                              hipStream_t stream) {
    const float* pred   = (const float*)d_in[0];
    const float* target = (const float*)d_in[1];
    const int*   choice = (const int*)d_in[2];
    float* out = (float*)d_out;
    float* ws  = (float*)d_ws;

    int ncells  = in_sizes[2];                   // BATCH * S * S = 802816
    int nchunks = (ncells + CPB - 1) / CPB;      // 6272 exactly
    int grid    = GRID < nchunks ? GRID : nchunks;
    // ws usage: GRID * ROW * 4 B = 40 KB; rows [0,grid) all written before read
    yolo_main<<<grid, T, 0, stream>>>(pred, target, choice, ws, ncells, nchunks);
    yolo_reduce<<<1, 256, 0, stream>>>(ws, out, grid);
}